// Round 4
// baseline (181.150 us; speedup 1.0000x reference)
//
#include <hip/hip_runtime.h>
#include <hip/hip_bf16.h>
#include <math.h>

// Problem constants
#define Bb   4
#define Cc   128
#define Nn   4096          // 64*64 spatial
#define BN   (Bb * Nn)
#define HP   0.1f
#define EPSN 1e-10f
#define EPSM 0.001f

typedef __attribute__((ext_vector_type(8))) short short8;  // 8 bf16 = 4 VGPRs
typedef __attribute__((ext_vector_type(4))) float f32x4;   // MFMA accumulator

// Workspace layout (float offsets)
#define OFF_MEAN 0                 // [B*C]    = 512   (atomicAdd -> zeroed)
#define OFF_ACC  512               // [B]      = 4     (atomicAdd -> zeroed)
#define OFF_CTV  1024              // [B*N*2]  = 32768 (fully overwritten) {c0,c1}
#define OFF_PMAX 33792             // [8][B*N] = 131072 (fully overwritten)
#define OFF_SSP  164864            // [8][B*N] = 131072 (fully overwritten)
#define OFF_FXN  295936            // bf16 [B*N*C] = 1048576 floats
#define OFF_FYN  1344512           // bf16 [B*N*C]

// async global -> LDS, 16B per lane; LDS dest = wave-uniform base + lane*16
__device__ __forceinline__ void gload_lds16(const void* g, void* l)
{
    __builtin_amdgcn_global_load_lds(
        (const __attribute__((address_space(1))) unsigned int*)g,
        (__attribute__((address_space(3))) unsigned int*)l, 16, 0, 0);
}

// ---------------------------------------------------------------------------
// Kernel 1: per-(b,c) sums of feature_y over spatial dim (atomicAdd partials)
__global__ void k_mean(const float* __restrict__ fy, float* __restrict__ mean)
{
    int b = blockIdx.x >> 5;
    int chunk = blockIdx.x & 31;
    int c = threadIdx.x;           // 128 threads, one per channel
    const float* p = fy + ((size_t)b * Nn + (size_t)chunk * 128) * Cc + c;
    float s = 0.f;
    for (int n = 0; n < 128; ++n) s += p[(size_t)n * Cc];
    atomicAdd(&mean[b * Cc + c], s);
}

// ---------------------------------------------------------------------------
// Kernel 2: center by spatial mean of y, L2-normalize each (b,n) vector over C,
// emit bf16. 256 threads = 4 waves, one wave per (b,n) row.
__global__ void k_norm(const float* __restrict__ fx, const float* __restrict__ fy,
                       const float* __restrict__ mean,
                       __hip_bfloat16* __restrict__ fxn, __hip_bfloat16* __restrict__ fyn)
{
    int bn = blockIdx.x * 4 + (threadIdx.x >> 6);   // 0 .. B*N-1
    int b = bn >> 12;
    int l = threadIdx.x & 63;
    const float* px = fx + (size_t)bn * Cc;
    const float* py = fy + (size_t)bn * Cc;
    const float* mp = mean + b * Cc;

    float m0 = mp[l]      * (1.f / Nn);
    float m1 = mp[l + 64] * (1.f / Nn);
    float x0 = px[l] - m0, x1 = px[l + 64] - m1;
    float y0 = py[l] - m0, y1 = py[l + 64] - m1;
    float sx = x0 * x0 + x1 * x1;
    float sy = y0 * y0 + y1 * y1;
    #pragma unroll
    for (int o = 32; o > 0; o >>= 1) {
        sx += __shfl_xor(sx, o);
        sy += __shfl_xor(sy, o);
    }
    float ix = 1.f / (sqrtf(sx) + EPSN);
    float iy = 1.f / (sqrtf(sy) + EPSN);
    fxn[(size_t)bn * Cc + l]      = __float2bfloat16(x0 * ix);
    fxn[(size_t)bn * Cc + l + 64] = __float2bfloat16(x1 * ix);
    fyn[(size_t)bn * Cc + l]      = __float2bfloat16(y0 * iy);
    fyn[(size_t)bn * Cc + l + 64] = __float2bfloat16(y1 * iy);
}

// ---------------------------------------------------------------------------
// MFMA core: per batch, S = X · Y^T  (M=N=4096, K=C=128).
// Block = 128-row strip of A (staged once) x 4 m-tiles of B (looped).
// LDS layout XOR-swizzled: chunk16 c of row r stored at slot c^(r&15)
// -> staging is lane-linear (global_load_lds ok), ds_read_b128 is 2-way (free).
// PASS 1: per-row running max of dot -> pmax[my][b*N+row]
// PASS 2: per-row running sum of exp(fma(dot,c1,c0)) -> ssp[my][b*N+row]
// Register budget note: loop-carried state is acc(64) + fold(16) only; the
// exp coefficients are read from LDS at fold time (round-3 kept them in
// VGPRs -> scratch spill, 104 MB/dispatch of HBM write traffic).
template <int PASS>
__global__ __launch_bounds__(256, 2) void k_gemm(
    const ushort* __restrict__ fxn, const ushort* __restrict__ fyn,
    float* __restrict__ pmax, const float* __restrict__ ctv,
    float* __restrict__ ssp)
{
    __shared__ ushort sA[128 * 128];
    __shared__ ushort sB[128 * 128];
    __shared__ float  sred[128 * 2];
    __shared__ float  sctv[128 * 2];

    const int tid  = threadIdx.x;
    const int lane = tid & 63;
    const int w    = tid >> 6;
    const int n0   = blockIdx.x * 128;
    const int my   = blockIdx.y;          // 0..7 -> m-tiles my*4 .. my*4+3
    const int b    = blockIdx.z;

    const ushort* gA = fxn + (size_t)b * Nn * Cc;
    const ushort* gB = fyn + (size_t)b * Nn * Cc;

    if (PASS == 2 && tid < 128)
        ((float2*)sctv)[tid] = ((const float2*)ctv)[b * Nn + n0 + tid];

    // Stage A tile once: 2048 chunk16s; wave w covers linear slots w*512+inst*64+lane.
    #pragma unroll
    for (int inst = 0; inst < 8; ++inst) {
        int L0 = w * 512 + inst * 64;
        int L  = L0 + lane;
        int r = L >> 4, s = L & 15;
        int c = s ^ (r & 15);
        gload_lds16(gA + (size_t)(n0 + r) * Cc + c * 8, &sA[L0 * 8]);
    }

    const int l15 = lane & 15, q = lane >> 4;
    const int wy = w >> 1, wx = w & 1;     // wave's 64x64 quadrant

    float fold[4][4];                      // PASS1: running max; PASS2: exp-sum
    #pragma unroll
    for (int i = 0; i < 4; ++i)
        #pragma unroll
        for (int r = 0; r < 4; ++r) fold[i][r] = (PASS == 1) ? -1e30f : 0.f;

    #pragma unroll
    for (int mt = 0; mt < 4; ++mt) {
        const int m0 = (my * 4 + mt) * 128;
        // Stage B tile for this m-tile.
        #pragma unroll
        for (int inst = 0; inst < 8; ++inst) {
            int L0 = w * 512 + inst * 64;
            int L  = L0 + lane;
            int r = L >> 4, s = L & 15;
            int c = s ^ (r & 15);
            gload_lds16(gB + (size_t)(m0 + r) * Cc + c * 8, &sB[L0 * 8]);
        }
        __syncthreads();   // drains vmcnt: staging complete; sctv visible

        f32x4 acc[4][4];
        #pragma unroll
        for (int i = 0; i < 4; ++i)
            #pragma unroll
            for (int j = 0; j < 4; ++j)
                acc[i][j] = (f32x4){0.f, 0.f, 0.f, 0.f};

        #pragma unroll
        for (int kt = 0; kt < 4; ++kt) {
            short8 a[4], bb[4];
            const int sw = ((kt * 4 + q) ^ l15) * 8;   // swizzled chunk offset
            #pragma unroll
            for (int i = 0; i < 4; ++i)
                a[i] = *(const short8*)&sA[(wy * 64 + i * 16 + l15) * 128 + sw];
            #pragma unroll
            for (int j = 0; j < 4; ++j)
                bb[j] = *(const short8*)&sB[(wx * 64 + j * 16 + l15) * 128 + sw];
            #pragma unroll
            for (int i = 0; i < 4; ++i)
                #pragma unroll
                for (int j = 0; j < 4; ++j)
                    acc[i][j] = __builtin_amdgcn_mfma_f32_16x16x32_bf16(
                        a[i], bb[j], acc[i][j], 0, 0, 0);
        }

        // Fold this m-tile into running per-row state.
        // C/D layout: col = lane&15, row = (lane>>4)*4 + reg  [m89-verified]
        #pragma unroll
        for (int i = 0; i < 4; ++i)
            #pragma unroll
            for (int r = 0; r < 4; ++r) {
                if (PASS == 1) {
                    float v = acc[i][0][r];
                    #pragma unroll
                    for (int j = 1; j < 4; ++j) v = fmaxf(v, acc[i][j][r]);
                    fold[i][r] = fmaxf(fold[i][r], v);
                } else {
                    int row = wy * 64 + i * 16 + q * 4 + r;
                    float2 cc = *(const float2*)&sctv[row * 2];  // {c0, c1}
                    float s = 0.f;
                    #pragma unroll
                    for (int j = 0; j < 4; ++j)
                        s += __expf(fmaf(acc[i][j][r], cc.y, cc.x));  // arg <= ~0
                    fold[i][r] += s;
                }
            }
        __syncthreads();   // all waves done reading sB before next staging
    }

    // Per-row reduction across the 16 columns (l15) and the wx wave pair.
    #pragma unroll
    for (int i = 0; i < 4; ++i)
        #pragma unroll
        for (int r = 0; r < 4; ++r) {
            float v = fold[i][r];
            if (PASS == 1) {
                #pragma unroll
                for (int o = 1; o < 16; o <<= 1) v = fmaxf(v, __shfl_xor(v, o));
            } else {
                #pragma unroll
                for (int o = 1; o < 16; o <<= 1) v += __shfl_xor(v, o);
            }
            if (l15 == 0) sred[(wy * 64 + i * 16 + q * 4 + r) * 2 + wx] = v;
        }
    __syncthreads();
    if (tid < 128) {
        if (PASS == 1)
            pmax[(size_t)my * BN + b * Nn + n0 + tid] =
                fmaxf(sred[tid * 2], sred[tid * 2 + 1]);
        else
            ssp[(size_t)my * BN + b * Nn + n0 + tid] =
                sred[tid * 2] + sred[tid * 2 + 1];
    }
}

// ---------------------------------------------------------------------------
// Reduce 8 max partials -> affine exp coefficients {c0,c1} per row
//   d = 1 - max dot; t = 1/(HP*(d+eps)); arg(dot) = (d - (1-dot))*t = dot*t + (d-1)*t
__global__ void k_dmin(const float* __restrict__ pmax, float* __restrict__ ctv)
{
    int i = blockIdx.x * 256 + threadIdx.x;   // 0 .. B*N-1
    float g = -1e30f;
    #pragma unroll
    for (int z = 0; z < 8; ++z) g = fmaxf(g, pmax[(size_t)z * BN + i]);
    float d = 1.f - g;
    float t = 1.f / (HP * (d + EPSM));
    ((float2*)ctv)[i] = (float2){(d - 1.f) * t, t};
}

// ---------------------------------------------------------------------------
// Stage 1 of final reduction: per-row 1/s, block-sum, atomicAdd per batch.
__global__ void k_partial(const float* __restrict__ ssp, float* __restrict__ acc)
{
    int i = blockIdx.x * 256 + threadIdx.x;   // 0 .. B*N-1 (block spans one batch)
    float t = 0.f;
    #pragma unroll
    for (int z = 0; z < 8; ++z) t += ssp[(size_t)z * BN + i];
    float s = 1.f / t;
    #pragma unroll
    for (int o = 32; o > 0; o >>= 1) s += __shfl_xor(s, o);
    __shared__ float red[4];
    if ((threadIdx.x & 63) == 0) red[threadIdx.x >> 6] = s;
    __syncthreads();
    if (threadIdx.x == 0)
        atomicAdd(&acc[i >> 12], red[0] + red[1] + red[2] + red[3]);
}

__global__ void k_out(const float* __restrict__ acc, float* __restrict__ out)
{
    int b = threadIdx.x;
    if (b < Bb) out[b] = -logf(acc[b] * (1.f / Nn));
}

// ---------------------------------------------------------------------------
extern "C" void kernel_launch(void* const* d_in, const int* in_sizes, int n_in,
                              void* d_out, int out_size, void* d_ws, size_t ws_size,
                              hipStream_t stream)
{
    const float* fx = (const float*)d_in[0];
    const float* fy = (const float*)d_in[1];
    float* out = (float*)d_out;
    float* ws  = (float*)d_ws;

    float* mean = ws + OFF_MEAN;
    float* acc  = ws + OFF_ACC;
    float* ctv  = ws + OFF_CTV;
    float* pmax = ws + OFF_PMAX;
    float* ssp  = ws + OFF_SSP;
    __hip_bfloat16* fxn = (__hip_bfloat16*)(ws + OFF_FXN);
    __hip_bfloat16* fyn = (__hip_bfloat16*)(ws + OFF_FYN);

    // zero the atomicAdd accumulators (mean @0..511, acc @512..515)
    hipMemsetAsync(ws, 0, 516 * sizeof(float), stream);

    k_mean<<<dim3(Bb * 32), dim3(128), 0, stream>>>(fy, mean);
    k_norm<<<dim3(Bb * Nn / 4), dim3(256), 0, stream>>>(fx, fy, mean, fxn, fyn);

    dim3 gg(32, 8, Bb);   // 1024 blocks, 2/CU for the 66 KB LDS footprint
    k_gemm<1><<<gg, dim3(256), 0, stream>>>((const ushort*)fxn, (const ushort*)fyn,
                                            pmax, nullptr, nullptr);
    k_dmin<<<dim3(BN / 256), dim3(256), 0, stream>>>(pmax, ctv);
    k_gemm<2><<<gg, dim3(256), 0, stream>>>((const ushort*)fxn, (const ushort*)fyn,
                                            nullptr, ctv, ssp);
    k_partial<<<dim3(BN / 256), dim3(256), 0, stream>>>(ssp, acc);
    k_out<<<dim3(1), dim3(64), 0, stream>>>(acc, out);
}

// Round 5
// 175.731 us; speedup vs baseline: 1.0308x; 1.0308x over previous
//
#include <hip/hip_runtime.h>
#include <hip/hip_bf16.h>
#include <math.h>

// Problem constants
#define Bb   4
#define Cc   128
#define Nn   4096          // 64*64 spatial
#define BN   (Bb * Nn)
#define HP   0.1f
#define EPSN 1e-10f
#define EPSM 0.001f

typedef __attribute__((ext_vector_type(8))) short short8;  // 8 bf16 = 4 VGPRs
typedef __attribute__((ext_vector_type(4))) float f32x4;   // MFMA accumulator

// Workspace layout (float offsets)
#define OFF_MEAN 0                 // [B*C]    = 512   (atomicAdd -> zeroed)
#define OFF_ACC  512               // [B]      = 4     (atomicAdd -> zeroed)
#define OFF_CTV  1024              // [B*N*2]  = 32768 (fully overwritten) {c0,c1}
#define OFF_PMAX 33792             // [8][B*N] = 131072 (fully overwritten)
#define OFF_SSP  164864            // [8][B*N] = 131072 (fully overwritten)
#define OFF_FXN  295936            // bf16 [B*N*C] = 1048576 floats
#define OFF_FYN  1344512           // bf16 [B*N*C]

// ---------------------------------------------------------------------------
// Kernel 1: per-(b,c) sums of feature_y over spatial dim (atomicAdd partials)
__global__ void k_mean(const float* __restrict__ fy, float* __restrict__ mean)
{
    int b = blockIdx.x >> 5;
    int chunk = blockIdx.x & 31;
    int c = threadIdx.x;           // 128 threads, one per channel
    const float* p = fy + ((size_t)b * Nn + (size_t)chunk * 128) * Cc + c;
    float s = 0.f;
    for (int n = 0; n < 128; ++n) s += p[(size_t)n * Cc];
    atomicAdd(&mean[b * Cc + c], s);
}

// ---------------------------------------------------------------------------
// Kernel 2: center by spatial mean of y, L2-normalize each (b,n) vector over C,
// emit bf16. 256 threads = 4 waves, one wave per (b,n) row.
__global__ void k_norm(const float* __restrict__ fx, const float* __restrict__ fy,
                       const float* __restrict__ mean,
                       __hip_bfloat16* __restrict__ fxn, __hip_bfloat16* __restrict__ fyn)
{
    int bn = blockIdx.x * 4 + (threadIdx.x >> 6);   // 0 .. B*N-1
    int b = bn >> 12;
    int l = threadIdx.x & 63;
    const float* px = fx + (size_t)bn * Cc;
    const float* py = fy + (size_t)bn * Cc;
    const float* mp = mean + b * Cc;

    float m0 = mp[l]      * (1.f / Nn);
    float m1 = mp[l + 64] * (1.f / Nn);
    float x0 = px[l] - m0, x1 = px[l + 64] - m1;
    float y0 = py[l] - m0, y1 = py[l + 64] - m1;
    float sx = x0 * x0 + x1 * x1;
    float sy = y0 * y0 + y1 * y1;
    #pragma unroll
    for (int o = 32; o > 0; o >>= 1) {
        sx += __shfl_xor(sx, o);
        sy += __shfl_xor(sy, o);
    }
    float ix = 1.f / (sqrtf(sx) + EPSN);
    float iy = 1.f / (sqrtf(sy) + EPSN);
    fxn[(size_t)bn * Cc + l]      = __float2bfloat16(x0 * ix);
    fxn[(size_t)bn * Cc + l + 64] = __float2bfloat16(x1 * ix);
    fyn[(size_t)bn * Cc + l]      = __float2bfloat16(y0 * iy);
    fyn[(size_t)bn * Cc + l + 64] = __float2bfloat16(y1 * iy);
}

// ---------------------------------------------------------------------------
// MFMA core: per batch, S = X · Y^T  (M=N=4096, K=C=128).
// Block = 128-row strip of A (staged once) x 4 m-tiles of B (pipelined loop).
// Staging: linear float4 global loads -> ds_write_b128 at XOR-swizzled LDS
// slot c^(r&15)  (writes 2-way bank-aliased = free; frag reads 2-way = free).
// Next B tile is prefetched into VGPRs during the current tile's MFMAs.
// PASS 1: per-row running max of dot -> pmax[my][b*N+row]
// PASS 2: per-row running sum of exp(fma(dot,c1,c0)) -> ssp[my][b*N+row]
// launch_bounds(256,1): 512-VGPR cap. Rounds 1/3/4 showed the compiler pins
// VGPR=128 under (256,2) and scratch-spills (100+ MB HBM writes/dispatch).
// LDS (66 KB) caps residency at 2 blocks/CU regardless, so no occupancy loss.
template <int PASS>
__global__ __launch_bounds__(256, 1) void k_gemm(
    const ushort* __restrict__ fxn, const ushort* __restrict__ fyn,
    float* __restrict__ pmax, const float* __restrict__ ctv,
    float* __restrict__ ssp)
{
    __shared__ ushort sA[128 * 128];
    __shared__ ushort sB[128 * 128];
    __shared__ float  sred[128 * 2];
    __shared__ float  sctv[128 * 2];

    const int tid  = threadIdx.x;
    const int lane = tid & 63;
    const int w    = tid >> 6;
    const int n0   = blockIdx.x * 128;
    const int my   = blockIdx.y;          // 0..7 -> m-tiles my*4 .. my*4+3
    const int b    = blockIdx.z;

    const float4* gA4 = (const float4*)(fxn + (size_t)b * Nn * Cc);  // 16 chunks/row
    const float4* gB4 = (const float4*)(fyn + (size_t)b * Nn * Cc);

    if (PASS == 2 && tid < 128)
        ((float2*)sctv)[tid] = ((const float2*)ctv)[b * Nn + n0 + tid];

    // Per-thread staging geometry: thread covers chunks cid = tid + 256*it,
    // row r = r0 + 16*it (r0 = tid>>4), chunk s = tid&15 (const), and the
    // XOR slot sx = s ^ (r&15) = s ^ (r0&15) is also constant across it.
    const int r0 = tid >> 4, s = tid & 15;
    const int sx = s ^ (r0 & 15);
    const int go = r0 * 16 + s;            // global float4 index base within tile
    const int lo = r0 * 128 + sx * 8;      // LDS ushort offset base

    // Stage A tile once (load+write fused; latency exposed once per block).
    #pragma unroll
    for (int it = 0; it < 8; ++it)
        *(float4*)&sA[lo + 2048 * it] = gA4[(size_t)(n0 * 16) + go + 256 * it];

    // Prefetch B tile 0 into VGPRs.
    float4 pb[8];
    {
        const int m0 = (my * 4) * 128;
        #pragma unroll
        for (int it = 0; it < 8; ++it)
            pb[it] = gB4[(size_t)(m0 * 16) + go + 256 * it];
    }

    const int l15 = lane & 15, q = lane >> 4;
    const int wy = w >> 1, wx = w & 1;     // wave's 64x64 quadrant

    float fold[4][4];                      // PASS1: running max; PASS2: exp-sum
    #pragma unroll
    for (int i = 0; i < 4; ++i)
        #pragma unroll
        for (int r = 0; r < 4; ++r) fold[i][r] = (PASS == 1) ? -1e30f : 0.f;

    #pragma unroll 1
    for (int mt = 0; mt < 4; ++mt) {
        // Commit prefetched B tile to LDS.
        #pragma unroll
        for (int it = 0; it < 8; ++it)
            *(float4*)&sB[lo + 2048 * it] = pb[it];
        __syncthreads();   // A (first iter) + B staged; sctv visible

        // Prefetch next B tile; overlaps the MFMA section below.
        if (mt < 3) {
            const int m0 = (my * 4 + mt + 1) * 128;
            #pragma unroll
            for (int it = 0; it < 8; ++it)
                pb[it] = gB4[(size_t)(m0 * 16) + go + 256 * it];
        }

        f32x4 acc[4][4];
        #pragma unroll
        for (int i = 0; i < 4; ++i)
            #pragma unroll
            for (int j = 0; j < 4; ++j)
                acc[i][j] = (f32x4){0.f, 0.f, 0.f, 0.f};

        #pragma unroll
        for (int kt = 0; kt < 4; ++kt) {
            short8 a[4], bb[4];
            const int sw = ((kt * 4 + q) ^ l15) * 8;   // swizzled chunk offset
            #pragma unroll
            for (int i = 0; i < 4; ++i)
                a[i] = *(const short8*)&sA[(wy * 64 + i * 16 + l15) * 128 + sw];
            #pragma unroll
            for (int j = 0; j < 4; ++j)
                bb[j] = *(const short8*)&sB[(wx * 64 + j * 16 + l15) * 128 + sw];
            #pragma unroll
            for (int i = 0; i < 4; ++i)
                #pragma unroll
                for (int j = 0; j < 4; ++j)
                    acc[i][j] = __builtin_amdgcn_mfma_f32_16x16x32_bf16(
                        a[i], bb[j], acc[i][j], 0, 0, 0);
        }

        // Fold this m-tile into running per-row state.
        // C/D layout: col = lane&15, row = (lane>>4)*4 + reg  [m89-verified]
        #pragma unroll
        for (int i = 0; i < 4; ++i)
            #pragma unroll
            for (int r = 0; r < 4; ++r) {
                if (PASS == 1) {
                    float v = acc[i][0][r];
                    #pragma unroll
                    for (int j = 1; j < 4; ++j) v = fmaxf(v, acc[i][j][r]);
                    fold[i][r] = fmaxf(fold[i][r], v);
                } else {
                    int row = wy * 64 + i * 16 + q * 4 + r;
                    float2 cc = *(const float2*)&sctv[row * 2];  // {c0, c1}
                    float sum = 0.f;
                    #pragma unroll
                    for (int j = 0; j < 4; ++j)
                        sum += __expf(fmaf(acc[i][j][r], cc.y, cc.x));  // arg <= ~0
                    fold[i][r] += sum;
                }
            }
        __syncthreads();   // all waves done reading sB before next commit
    }

    // Per-row reduction across the 16 columns (l15) and the wx wave pair.
    #pragma unroll
    for (int i = 0; i < 4; ++i)
        #pragma unroll
        for (int r = 0; r < 4; ++r) {
            float v = fold[i][r];
            if (PASS == 1) {
                #pragma unroll
                for (int o = 1; o < 16; o <<= 1) v = fmaxf(v, __shfl_xor(v, o));
            } else {
                #pragma unroll
                for (int o = 1; o < 16; o <<= 1) v += __shfl_xor(v, o);
            }
            if (l15 == 0) sred[(wy * 64 + i * 16 + q * 4 + r) * 2 + wx] = v;
        }
    __syncthreads();
    if (tid < 128) {
        if (PASS == 1)
            pmax[(size_t)my * BN + b * Nn + n0 + tid] =
                fmaxf(sred[tid * 2], sred[tid * 2 + 1]);
        else
            ssp[(size_t)my * BN + b * Nn + n0 + tid] =
                sred[tid * 2] + sred[tid * 2 + 1];
    }
}

// ---------------------------------------------------------------------------
// Reduce 8 max partials -> affine exp coefficients {c0,c1} per row
//   d = 1 - max dot; t = 1/(HP*(d+eps)); arg(dot) = dot*t + (d-1)*t
__global__ void k_dmin(const float* __restrict__ pmax, float* __restrict__ ctv)
{
    int i = blockIdx.x * 256 + threadIdx.x;   // 0 .. B*N-1
    float g = -1e30f;
    #pragma unroll
    for (int z = 0; z < 8; ++z) g = fmaxf(g, pmax[(size_t)z * BN + i]);
    float d = 1.f - g;
    float t = 1.f / (HP * (d + EPSM));
    ((float2*)ctv)[i] = (float2){(d - 1.f) * t, t};
}

// ---------------------------------------------------------------------------
// Stage 1 of final reduction: per-row 1/s, block-sum, atomicAdd per batch.
__global__ void k_partial(const float* __restrict__ ssp, float* __restrict__ acc)
{
    int i = blockIdx.x * 256 + threadIdx.x;   // 0 .. B*N-1 (block spans one batch)
    float t = 0.f;
    #pragma unroll
    for (int z = 0; z < 8; ++z) t += ssp[(size_t)z * BN + i];
    float s = 1.f / t;
    #pragma unroll
    for (int o = 32; o > 0; o >>= 1) s += __shfl_xor(s, o);
    __shared__ float red[4];
    if ((threadIdx.x & 63) == 0) red[threadIdx.x >> 6] = s;
    __syncthreads();
    if (threadIdx.x == 0)
        atomicAdd(&acc[i >> 12], red[0] + red[1] + red[2] + red[3]);
}

__global__ void k_out(const float* __restrict__ acc, float* __restrict__ out)
{
    int b = threadIdx.x;
    if (b < Bb) out[b] = -logf(acc[b] * (1.f / Nn));
}

// ---------------------------------------------------------------------------
extern "C" void kernel_launch(void* const* d_in, const int* in_sizes, int n_in,
                              void* d_out, int out_size, void* d_ws, size_t ws_size,
                              hipStream_t stream)
{
    const float* fx = (const float*)d_in[0];
    const float* fy = (const float*)d_in[1];
    float* out = (float*)d_out;
    float* ws  = (float*)d_ws;

    float* mean = ws + OFF_MEAN;
    float* acc  = ws + OFF_ACC;
    float* ctv  = ws + OFF_CTV;
    float* pmax = ws + OFF_PMAX;
    float* ssp  = ws + OFF_SSP;
    __hip_bfloat16* fxn = (__hip_bfloat16*)(ws + OFF_FXN);
    __hip_bfloat16* fyn = (__hip_bfloat16*)(ws + OFF_FYN);

    // zero the atomicAdd accumulators (mean @0..511, acc @512..515)
    hipMemsetAsync(ws, 0, 516 * sizeof(float), stream);

    k_mean<<<dim3(Bb * 32), dim3(128), 0, stream>>>(fy, mean);
    k_norm<<<dim3(Bb * Nn / 4), dim3(256), 0, stream>>>(fx, fy, mean, fxn, fyn);

    dim3 gg(32, 8, Bb);   // 1024 blocks, 2/CU (66 KB LDS)
    k_gemm<1><<<gg, dim3(256), 0, stream>>>((const ushort*)fxn, (const ushort*)fyn,
                                            pmax, nullptr, nullptr);
    k_dmin<<<dim3(BN / 256), dim3(256), 0, stream>>>(pmax, ctv);
    k_gemm<2><<<gg, dim3(256), 0, stream>>>((const ushort*)fxn, (const ushort*)fyn,
                                            nullptr, ctv, ssp);
    k_partial<<<dim3(BN / 256), dim3(256), 0, stream>>>(ssp, acc);
    k_out<<<dim3(1), dim3(64), 0, stream>>>(acc, out);
}